// Round 10
// baseline (3486.905 us; speedup 1.0000x reference)
//
#include <hip/hip_runtime.h>
#include <cstdint>
#include <cstddef>

// ---------------------------------------------------------------------------
// CapsNet forward, f32 end-to-end (precision-critical: the sort-based squash
// flips discrete segments on ~1e-7 perturbations of s_j, so no bf16 on that
// path).
//
// Workspace phases (floats), peak footprint 33.2M fl:
//   A (prim):    WT[0..5.31M] X1[5.31..20.05M] PU[20.05..33.16M]
//   B (ured):    U[33.16..34.80M]
//   C (uhat):    UHAT[0..32.77M] + U
//   D (routing): UHAT + smalls[32.77M..33.23M]
// ---------------------------------------------------------------------------

#define BATCH 100

static const size_t OFF_WT   = 0;            // 256*81*256 = 5,308,416   (dead after prim)
static const size_t OFF_X1   = 5308416;      // 100*256*576 = 14,745,600 (dead after prim)
static const size_t OFF_PU   = 20054016;     // 8*100*2048*8 = 13,107,200 (dead after k_ured)
static const size_t OFF_UHAT = 0;            // 100*2048*160 = 32,768,000
static const size_t OFF_U    = 33161216;     // 100*2048*8 = 1,638,400 (dead after k_uhat)
static const size_t OFF_BIJ  = 32768000;     // 2048*10
static const size_t OFF_CIJ  = 32788480;     // 2048*10
static const size_t OFF_SP   = 32808960;     // 100*16*160 = 256,000
static const size_t OFF_VJ   = 33064960;     // 100*160
static const size_t OFF_IDX  = 33080960;     // 100 ints (128 slots)
static const size_t OFF_H1   = 33081088;     // 100*512
static const size_t OFF_H2   = 33132288;     // 100*1024 -> end 33,234,688

// piecewise-affine squash constants
#define PT1f -13.46416092f
#define PA1f 0.000242759f
#define PB1f 0.024488359f
#define PA2f 0.002769205f
#define PB2f 0.06089699f
#define PT3f 13.23405266f
#define PA3f -0.002828244f
#define PB3f 0.061313814f
#define PA4f -0.000219038f
#define PB4f 0.023874787f

#define DT1f -0.075410217f
#define DA1f -0.074520095f
#define DB1f 0.349297946f
#define DA2f -0.534473989f
#define DB2f 0.27196494f
#define DT3f 0.062207676f
#define DA3f 0.637642944f
#define DB3f 0.295330779f
#define DA4f 0.169344703f
#define DB4f 0.353784456f

// x-row LDS placement for k_prim: STRICTLY INCREASING (injective) swizzle.
//   rowstart(r) = 12*r + 4*(r>>1)   (steps +12/+16 -> no collisions)
// Quad signature S(r) = (3r + (r>>1)) mod 8; rows read together differ by 2:
// S steps by 7 (coprime 8) -> 8 distinct bank-quads per read instr.
#define XROW(r) ((r) * 12 + ((r) >> 1) * 4)
#define XPH 332          // phase stride
#define XTB 664          // per-tb stride (2 phases)
#define XBUF (4 * XTB)   // per-LDS-buffer x size (2656 floats)
#define WBUF (81 * 32)   // per-LDS-buffer w size (2592 floats)

// ---------------------------------------------------------------------------
// w_t[(ci*81+tap)*256 + co]  <-  prim_w[co][ci][tap]
// ---------------------------------------------------------------------------
__global__ __launch_bounds__(256)
void k_transpose_w(const float* __restrict__ w, float* __restrict__ wt) {
  __shared__ float tile[64 * 82];
  int ci = blockIdx.x, co0 = blockIdx.y * 64, t = threadIdx.x;
  for (int f = t; f < 64 * 81; f += 256) {
    int col = f / 81, tap = f - col * 81;
    tile[col * 82 + tap] = w[(size_t)(co0 + col) * 20736 + (size_t)ci * 81 + tap];
  }
  __syncthreads();
  for (int g = t; g < 64 * 81; g += 256) {
    int tap = g / 64, col = g - tap * 64;
    wt[((size_t)ci * 81 + tap) * 256 + co0 + col] = tile[col * 82 + tap];
  }
}

// ---------------------------------------------------------------------------
// conv1 + bias + relu: data(100,1,32,32) -> x1(100,256,24,24)
// ---------------------------------------------------------------------------
__global__ __launch_bounds__(256)
void k_conv1(const float* __restrict__ data, const float* __restrict__ cw,
             const float* __restrict__ cb, float* __restrict__ x1) {
  __shared__ float img[1024];
  __shared__ float wl[81 * 32];     // [tap][c]
  int b = blockIdx.x, cg = blockIdx.y, t = threadIdx.x;
  for (int f = t; f < 1024; f += 256) img[f] = data[(size_t)b * 1024 + f];
  for (int f = t; f < 2592; f += 256) {
    int tap = f >> 5, c = f & 31;
    wl[f] = cw[(size_t)(cg * 32 + c) * 81 + tap];
  }
  __syncthreads();
  for (int task = t; task < 1152; task += 256) {
    int q = task % 144, cq = task / 144;
    int p0 = q * 4, oh = p0 / 24, ow0 = p0 % 24;
    float a[4][4];
#pragma unroll
    for (int i = 0; i < 4; ++i)
#pragma unroll
      for (int j = 0; j < 4; ++j) a[i][j] = 0.f;
    for (int kh = 0; kh < 9; ++kh) {
      const float* ir = &img[(oh + kh) * 32 + ow0];
      const float* wr = &wl[kh * 9 * 32 + cq * 4];
#pragma unroll
      for (int kw = 0; kw < 9; ++kw) {
        float4 wv = *(const float4*)(wr + kw * 32);
#pragma unroll
        for (int j = 0; j < 4; ++j) {
          float xv = ir[kw + j];
          a[0][j] = fmaf(wv.x, xv, a[0][j]);
          a[1][j] = fmaf(wv.y, xv, a[1][j]);
          a[2][j] = fmaf(wv.z, xv, a[2][j]);
          a[3][j] = fmaf(wv.w, xv, a[3][j]);
        }
      }
    }
#pragma unroll
    for (int cc = 0; cc < 4; ++cc) {
      int c = cg * 32 + cq * 4 + cc;
      float bias = cb[c];
      float4 o4 = make_float4(fmaxf(a[cc][0] + bias, 0.f), fmaxf(a[cc][1] + bias, 0.f),
                              fmaxf(a[cc][2] + bias, 0.f), fmaxf(a[cc][3] + bias, 0.f));
      *(float4*)&x1[((size_t)(b * 256 + c) * 24 + oh) * 24 + ow0] = o4;
    }
  }
}

// ---------------------------------------------------------------------------
// prim conv v10: x1(100,256,24,24) -> PU[split](100,2048,8), 9x9 stride 2.
// Full LDS DOUBLE-BUFFER (x and w) + register prefetch, ONE barrier/iter:
//   iter k: issue loads(ci=k+1) -> compute buf[k&1] (hides latency)
//           -> commit to buf[(k+1)&1] -> barrier.
// LDS = 2*(10368+10624) = 41984 B -> 3 blocks/CU -> allocator targets
// 3 waves/EU -> ~168 VGPR budget -> prefetch regs fit, NO SPILL (R8/R9's
// 64-VGPR spill was the LDS-20992->7-waves/EU heuristic).
// FMA order per output identical to v7 -> bitwise-same partials.
// ---------------------------------------------------------------------------
__global__ __launch_bounds__(256)
void k_prim(const float* __restrict__ x1, const float* __restrict__ wt,
            float* __restrict__ pu) {
  __shared__ float wsh[2 * WBUF];       // 20736 B
  __shared__ float xsh[2 * XBUF];       // 21248 B
  int t = threadIdx.x;
  int tb = t >> 6, tl = t & 63;
  int coq = tl >> 3, oh = tl & 7;
  int ci_base = blockIdx.x * 32, cog = blockIdx.y, bq = blockIdx.z;
  int b = bq * 4 + tb;

  // ---- fixed per-thread staging jobs ----
  // x jobs (288 total): slot0 = t (always); slot1 = t+256 (t<32 only)
  int xt0 = t / 72, xm0 = t - xt0 * 72;
  int xr0 = xm0 / 3, xo0 = xm0 - xr0 * 3;
  const float* xg0 = x1 + ((size_t)(bq * 4 + xt0) * 256 + ci_base) * 576 + xr0 * 24 + xo0 * 8;
  int xoff0 = xt0 * XTB + XROW(xr0) + xo0 * 4;
  int f1 = t + 256;
  int xt1 = f1 / 72, xm1 = f1 - xt1 * 72;
  int xr1 = xm1 / 3, xo1 = xm1 - xr1 * 3;
  bool hx1 = (t < 32);
  const float* xg1 = x1 + ((size_t)(bq * 4 + xt1) * 256 + ci_base) * 576 + xr1 * 24 + xo1 * 8;
  int xoff1 = xt1 * XTB + XROW(xr1) + xo1 * 4;
  // w jobs (648 total): slots t, t+256, t+512 (third only t<136)
  const float* wg0 = wt + ((size_t)ci_base * 81 + (t >> 3)) * 256 + cog * 32 + (t & 7) * 4;
  int woff = (t >> 3) * 32 + (t & 7) * 4;
  bool hw2 = (t < 136);

  float acc[4][8];
#pragma unroll
  for (int i = 0; i < 4; ++i)
#pragma unroll
    for (int j = 0; j < 8; ++j) acc[i][j] = 0.f;

  // prologue: stage ci_base into buffer 0
  {
    float4 a0 = *(const float4*)xg0, b0 = *(const float4*)(xg0 + 4);
    float* d0 = &xsh[xoff0];
    *(float4*)d0 = make_float4(a0.x, a0.z, b0.x, b0.z);
    *(float4*)(d0 + XPH) = make_float4(a0.y, a0.w, b0.y, b0.w);
    if (hx1) {
      float4 a1 = *(const float4*)xg1, b1 = *(const float4*)(xg1 + 4);
      float* d1 = &xsh[xoff1];
      *(float4*)d1 = make_float4(a1.x, a1.z, b1.x, b1.z);
      *(float4*)(d1 + XPH) = make_float4(a1.y, a1.w, b1.y, b1.w);
    }
    float* wd = &wsh[woff];
    *(float4*)wd = *(const float4*)wg0;
    *(float4*)(wd + 32 * 32) = *(const float4*)(wg0 + 32 * 256);
    if (hw2) *(float4*)(wd + 64 * 32) = *(const float4*)(wg0 + 64 * 256);
  }
  __syncthreads();

#pragma unroll 1
  for (int k = 0; k < 32; ++k) {
    int cur = k & 1;
    // issue prefetch for ci = ci_base+k+1; latency hides behind FMAs below
    float4 pxa0, pxb0, pxa1, pxb1, pw0, pw1, pw2;
    if (k < 31) {
      xg0 += 576; xg1 += 576; wg0 += 81 * 256;
      pxa0 = *(const float4*)xg0; pxb0 = *(const float4*)(xg0 + 4);
      if (hx1) { pxa1 = *(const float4*)xg1; pxb1 = *(const float4*)(xg1 + 4); }
      pw0 = *(const float4*)wg0;
      pw1 = *(const float4*)(wg0 + 32 * 256);
      if (hw2) pw2 = *(const float4*)(wg0 + 64 * 256);
    }
    // compute on buf[cur]: kh fully unrolled -> immediate ds_read offsets
    const float* xb = &xsh[cur * XBUF + tb * XTB] + XROW(2 * oh);
    const float* wb = &wsh[cur * WBUF + coq * 4];
#pragma unroll
    for (int kh = 0; kh < 9; ++kh) {
      const float* xe = xb + (12 * kh + 4 * (kh >> 1));
      float ew[12], ov[12];
      *(float4*)&ew[0] = *(const float4*)xe;
      *(float4*)&ew[4] = *(const float4*)(xe + 4);
      *(float4*)&ew[8] = *(const float4*)(xe + 8);
      *(float4*)&ov[0] = *(const float4*)(xe + XPH);
      *(float4*)&ov[4] = *(const float4*)(xe + XPH + 4);
      *(float4*)&ov[8] = *(const float4*)(xe + XPH + 8);
      const float* wr = wb + kh * 288;
#pragma unroll
      for (int p = 0; p < 5; ++p) {                 // kw = 2p (even cols)
        float4 wv = *(const float4*)(wr + p * 64);
#pragma unroll
        for (int j = 0; j < 8; ++j) {
          float xv = ew[p + j];
          acc[0][j] = fmaf(wv.x, xv, acc[0][j]);
          acc[1][j] = fmaf(wv.y, xv, acc[1][j]);
          acc[2][j] = fmaf(wv.z, xv, acc[2][j]);
          acc[3][j] = fmaf(wv.w, xv, acc[3][j]);
        }
      }
#pragma unroll
      for (int p = 0; p < 4; ++p) {                 // kw = 2p+1 (odd cols)
        float4 wv = *(const float4*)(wr + 32 + p * 64);
#pragma unroll
        for (int j = 0; j < 8; ++j) {
          float xv = ov[p + j];
          acc[0][j] = fmaf(wv.x, xv, acc[0][j]);
          acc[1][j] = fmaf(wv.y, xv, acc[1][j]);
          acc[2][j] = fmaf(wv.z, xv, acc[2][j]);
          acc[3][j] = fmaf(wv.w, xv, acc[3][j]);
        }
      }
    }
    // commit prefetched tiles to the OTHER buffer; one barrier per iter
    if (k < 31) {
      int nb = (cur ^ 1);
      float* xd0 = &xsh[nb * XBUF + xoff0];
      *(float4*)xd0 = make_float4(pxa0.x, pxa0.z, pxb0.x, pxb0.z);
      *(float4*)(xd0 + XPH) = make_float4(pxa0.y, pxa0.w, pxb0.y, pxb0.w);
      if (hx1) {
        float* xd1 = &xsh[nb * XBUF + xoff1];
        *(float4*)xd1 = make_float4(pxa1.x, pxa1.z, pxb1.x, pxb1.z);
        *(float4*)(xd1 + XPH) = make_float4(pxa1.y, pxa1.w, pxb1.y, pxb1.w);
      }
      float* wd = &wsh[nb * WBUF + woff];
      *(float4*)wd = pw0;
      *(float4*)(wd + 32 * 32) = pw1;
      if (hw2) *(float4*)(wd + 64 * 32) = pw2;
      __syncthreads();
    }
  }
  // partial write (no bias; k_ured adds it): pu[split][b][r=co*8+oh][ow]
  float* pp = pu + (((size_t)blockIdx.x * BATCH + b) * 2048 +
                    (cog * 32 + coq * 4) * 8 + oh) * 8;
#pragma unroll
  for (int cc = 0; cc < 4; ++cc) {
    *(float4*)(pp + cc * 64)     = make_float4(acc[cc][0], acc[cc][1], acc[cc][2], acc[cc][3]);
    *(float4*)(pp + cc * 64 + 4) = make_float4(acc[cc][4], acc[cc][5], acc[cc][6], acc[cc][7]);
  }
}

// u = sum of 8 partials (ci-ascending order) + bias
__global__ __launch_bounds__(256)
void k_ured(const float* __restrict__ pu, const float* __restrict__ pb,
            float* __restrict__ u) {
  int g4 = blockIdx.x * 256 + threadIdx.x;     // 409,600 float4s
  if (g4 >= 409600) return;
  size_t g = (size_t)g4 * 4;
  const size_t S = 1638400;
  float4 s = *(const float4*)(pu + g);
#pragma unroll
  for (int k = 1; k < 8; ++k) {
    float4 p = *(const float4*)(pu + (size_t)k * S + g);
    s.x += p.x; s.y += p.y; s.z += p.z; s.w += p.w;
  }
  int r = (int)((g >> 3) & 2047);
  float bias = pb[r >> 3];
  float4 o = make_float4(s.x + bias, s.y + bias, s.z + bias, s.w + bias);
  *(float4*)(u + g) = o;
}

// ---------------------------------------------------------------------------
// primary squash: stable bitonic sort per batch row + exact where-chain,
// then u_sq = mag * u in place.
// ---------------------------------------------------------------------------
__global__ __launch_bounds__(256)
void k_squash(float* __restrict__ u) {
  __shared__ float kv[2048];
  __shared__ int kid[2048];
  __shared__ int red[256];
  int b = blockIdx.x, t = threadIdx.x;
  for (int r = t; r < 2048; r += 256) {
    kv[r] = u[((size_t)b * 2048 + r) * 8];
    kid[r] = r;
  }
  __syncthreads();
  for (int size = 2; size <= 2048; size <<= 1) {
    for (int stride = size >> 1; stride > 0; stride >>= 1) {
#pragma unroll 1
      for (int s = 0; s < 4; ++s) {
        int i = t + s * 256;
        int pos = 2 * i - (i & (stride - 1));
        int q = pos + stride;
        float va = kv[pos], vb = kv[q];
        int ia = kid[pos], ib = kid[q];
        bool gt = (va > vb) || (va == vb && ia > ib);
        bool up = ((pos & size) == 0);
        if (gt == up) { kv[pos] = vb; kv[q] = va; kid[pos] = ib; kid[q] = ia; }
      }
      __syncthreads();
    }
  }
  int loc = 0;
#pragma unroll
  for (int s = 0; s < 8; ++s) loc += (kv[t + s * 256] < PT1f) ? 1 : 0;
  red[t] = loc; __syncthreads();
  for (int off = 128; off; off >>= 1) { if (t < off) red[t] += red[t + off]; __syncthreads(); }
  int i1 = red[0]; __syncthreads();
  float m1v[8];
  loc = 0;
#pragma unroll
  for (int s = 0; s < 8; ++s) {
    int p = t + s * 256;
    float v = kv[p];
    float m = (p < i1 - 1) ? (PA1f * v + PB1f) : v;
    m1v[s] = m;
    loc += (m < 0.f) ? 1 : 0;
  }
  red[t] = loc; __syncthreads();
  for (int off = 128; off; off >>= 1) { if (t < off) red[t] += red[t + off]; __syncthreads(); }
  int i2 = red[0]; __syncthreads();
  float m2v[8];
  loc = 0;
#pragma unroll
  for (int s = 0; s < 8; ++s) {
    int p = t + s * 256;
    float m = (p >= i1 && p < i2 - 1) ? (PA2f * m1v[s] + PB2f) : m1v[s];
    m2v[s] = m;
    loc += (m < PT3f) ? 1 : 0;
  }
  red[t] = loc; __syncthreads();
  for (int off = 128; off; off >>= 1) { if (t < off) red[t] += red[t + off]; __syncthreads(); }
  int i3 = red[0]; __syncthreads();
#pragma unroll
  for (int s = 0; s < 8; ++s) {
    int p = t + s * 256;
    float m = m2v[s];
    m = (p >= i2 && p < i3 - 1) ? (PA3f * m + PB3f) : m;
    m = (p >= i3 && p < 2047) ? (PA4f * m + PB4f) : m;
    int rid = kid[p];
    float* row = u + ((size_t)b * 2048 + rid) * 8;
    float4 lo = *(float4*)row;
    float4 hi = *(float4*)(row + 4);
    lo.x *= m; lo.y *= m; lo.z *= m; lo.w *= m;
    hi.x *= m; hi.y *= m; hi.z *= m; hi.w *= m;
    *(float4*)row = lo;
    *(float4*)(row + 4) = hi;
  }
}

// ---------------------------------------------------------------------------
// u_hat[b][r][c*16+o] = sum_i W_dc[r][c][o][i] * u_sq[b][r][i]
// ---------------------------------------------------------------------------
__global__ __launch_bounds__(192)
void k_uhat(const float* __restrict__ Wdc, const float* __restrict__ usq,
            float* __restrict__ uhat) {
  int t = threadIdx.x;
  if (t >= 160) return;
  int r0 = blockIdx.x * 8;
#pragma unroll 1
  for (int half = 0; half < 2; ++half) {
    int rb = r0 + half * 4;
    float4 wa[4], wb4[4];
#pragma unroll
    for (int rl = 0; rl < 4; ++rl) {
      const float* wp = Wdc + ((size_t)(rb + rl) * 160 + t) * 8;
      wa[rl]  = *(const float4*)wp;
      wb4[rl] = *(const float4*)(wp + 4);
    }
#pragma unroll 2
    for (int b = 0; b < BATCH; ++b) {
      const float* ub = usq + ((size_t)b * 2048 + rb) * 8;
      float* op = uhat + ((size_t)b * 2048 + rb) * 160 + t;
#pragma unroll
      for (int rl = 0; rl < 4; ++rl) {
        const float* us = ub + rl * 8;
        float v = us[0] * wa[rl].x + us[1] * wa[rl].y + us[2] * wa[rl].z + us[3] * wa[rl].w +
                  us[4] * wb4[rl].x + us[5] * wb4[rl].y + us[6] * wb4[rl].z + us[7] * wb4[rl].w;
        op[(size_t)rl * 160] = v;
      }
    }
  }
}

__global__ __launch_bounds__(256)
void k_softc(const float* __restrict__ bij, float* __restrict__ cij) {
  __shared__ float red[256];
  int c = blockIdx.x, t = threadIdx.x;
  float m = -3.402823466e38f;
  for (int r = t; r < 2048; r += 256) m = fmaxf(m, bij[r * 10 + c]);
  red[t] = m; __syncthreads();
  for (int off = 128; off; off >>= 1) { if (t < off) red[t] = fmaxf(red[t], red[t + off]); __syncthreads(); }
  m = red[0]; __syncthreads();
  float s = 0.f;
  for (int r = t; r < 2048; r += 256) s += expf(bij[r * 10 + c] - m);
  red[t] = s; __syncthreads();
  for (int off = 128; off; off >>= 1) { if (t < off) red[t] += red[t + off]; __syncthreads(); }
  s = red[0];
  for (int r = t; r < 2048; r += 256) cij[r * 10 + c] = expf(bij[r * 10 + c] - m) / s;
}

// it0: c_ij = softmax(zeros) = 1/2048 exactly -> uniform constant, no CIJ read
__global__ __launch_bounds__(192)
void k_sjpart(const float* __restrict__ cij, const float* __restrict__ uhat,
              float* __restrict__ sp, int it0) {
  __shared__ float cl[1280];
  int b = blockIdx.x, ch = blockIdx.y, t = threadIdx.x;
  if (!it0) {
    for (int f = t; f < 1280; f += 192) cl[f] = cij[(size_t)ch * 1280 + f];
  }
  __syncthreads();
  if (t < 160) {
    int c = t >> 4;
    float acc = 0.f;
    const float* up = uhat + ((size_t)b * 2048 + ch * 128) * 160 + t;
    if (it0) {
      const float cuni = 0.00048828125f;    // 1/2048 exact
#pragma unroll 4
      for (int rl = 0; rl < 128; ++rl) acc += cuni * up[(size_t)rl * 160];
    } else {
#pragma unroll 4
      for (int rl = 0; rl < 128; ++rl) acc += cl[rl * 10 + c] * up[(size_t)rl * 160];
    }
    sp[((size_t)b * 16 + ch) * 160 + t] = acc;
  }
}

__global__ __launch_bounds__(192)
void k_sjred(const float* __restrict__ sp, float* __restrict__ vj,
             float* __restrict__ dout, int finalit) {
  __shared__ float sl[160];
  __shared__ float fl[10];
  int b = blockIdx.x, t = threadIdx.x;
  if (t < 160) {
    float a = 0.f;
#pragma unroll
    for (int ch = 0; ch < 16; ++ch) a += sp[((size_t)b * 16 + ch) * 160 + t];
    sl[t] = a;
  }
  __syncthreads();
  if (t == 0) {
    float sv[10]; int rk[10];
    for (int c = 0; c < 10; ++c) sv[c] = sl[c * 16];
    for (int c = 0; c < 10; ++c) {
      int r = 0;
      for (int k = 0; k < 10; ++k)
        r += ((sv[k] < sv[c]) || (sv[k] == sv[c] && k < c)) ? 1 : 0;
      rk[c] = r;
    }
    int i1 = 0;
    for (int c = 0; c < 10; ++c) i1 += (sv[c] < DT1f) ? 1 : 0;
    float m1[10];
    for (int c = 0; c < 10; ++c) m1[c] = (rk[c] < i1 - 1) ? (DA1f * sv[c] + DB1f) : sv[c];
    int i2 = 0;
    for (int c = 0; c < 10; ++c) i2 += (m1[c] < 0.f) ? 1 : 0;
    float m2[10];
    for (int c = 0; c < 10; ++c)
      m2[c] = (rk[c] >= i1 && rk[c] < i2 - 1) ? (DA2f * m1[c] + DB2f) : m1[c];
    int i3 = 0;
    for (int c = 0; c < 10; ++c) i3 += (m2[c] < DT3f) ? 1 : 0;
    for (int c = 0; c < 10; ++c) {
      float m = (rk[c] >= i2 && rk[c] < i3 - 1) ? (DA3f * m2[c] + DB3f) : m2[c];
      m = (rk[c] >= i3 && rk[c] < 9) ? (DA4f * m + DB4f) : m;
      fl[c] = m;
    }
  }
  __syncthreads();
  if (t < 160) {
    int c = t >> 4, o = t & 15;
    float fv = fl[c];
    float v = fv * ((o == 0) ? fv : sl[t]);
    vj[(size_t)b * 160 + t] = v;
    if (finalit) dout[(size_t)b * 1184 + t] = v;
  }
}

// b-outer / r-inner -> per-b reads are 5120 B contiguous. Accumulation order
// per (r,t) unchanged (b-sequential, then o-shuffle).
__global__ __launch_bounds__(192)
void k_amean(const float* __restrict__ uhat, const float* __restrict__ vj,
             float* __restrict__ bij, int first) {
  __shared__ float vl[16000];
  int t = threadIdx.x, r0 = blockIdx.x * 8;
  for (int f = t; f < 16000; f += 192) vl[f] = vj[f];
  __syncthreads();
  if (t < 160) {
    int c = t >> 4;
    float acc[8];
#pragma unroll
    for (int rl = 0; rl < 8; ++rl) acc[rl] = 0.f;
    const float* up0 = uhat + (size_t)r0 * 160 + t;
#pragma unroll 2
    for (int b = 0; b < BATCH; ++b) {
      float vv = vl[b * 160 + t];
      const float* up = up0 + (size_t)b * 327680;
#pragma unroll
      for (int rl = 0; rl < 8; ++rl)
        acc[rl] = fmaf(up[(size_t)rl * 160], vv, acc[rl]);
    }
#pragma unroll
    for (int rl = 0; rl < 8; ++rl) {
      float a = acc[rl];
      for (int off = 8; off; off >>= 1) a += __shfl_down(a, off, 16);
      if ((t & 15) == 0) {
        int r = r0 + rl;
        float val = a / 100.0f;
        bij[r * 10 + c] = first ? val : (bij[r * 10 + c] + val);
      }
    }
  }
}

__global__ __launch_bounds__(256)
void k_cls(const float* __restrict__ vj, int* __restrict__ idxg) {
  __shared__ float cl[1000];
  __shared__ float cm[10];
  __shared__ float cs[10];
  int t = threadIdx.x;
  for (int f = t; f < 1000; f += 256) {
    int b = f / 10, c = f - b * 10;
    float s = 0.f;
#pragma unroll
    for (int o = 0; o < 16; ++o) {
      float v = vj[(size_t)b * 160 + c * 16 + o];
      s += v * v;
    }
    cl[f] = sqrtf(s);
  }
  __syncthreads();
  if (t < 10) {
    float m = -3.402823466e38f;
    for (int b = 0; b < BATCH; ++b) m = fmaxf(m, cl[b * 10 + t]);
    float s = 0.f;
    for (int b = 0; b < BATCH; ++b) s += expf(cl[b * 10 + t] - m);
    cm[t] = m; cs[t] = s;
  }
  __syncthreads();
  for (int b = t; b < BATCH; b += 256) {
    float best = -1.f; int bi = 0;
    for (int c = 0; c < 10; ++c) {
      float val = expf(cl[b * 10 + c] - cm[c]) / cs[c];
      if (val > best) { best = val; bi = c; }
    }
    idxg[b] = bi;
  }
}

__global__ __launch_bounds__(256)
void k_dec1(const float* __restrict__ w1, const float* __restrict__ b1,
            const float* __restrict__ vj, const int* __restrict__ idxg,
            float* __restrict__ h1) {
  int b = blockIdx.x, t = threadIdx.x;
  int id = idxg[b];
  const float* v = vj + (size_t)b * 160 + id * 16;
  for (int j = t; j < 512; j += 256) {
    float acc = b1[j];
    const float* wr = w1 + (size_t)j * 160 + id * 16;
#pragma unroll
    for (int o = 0; o < 16; ++o) acc += wr[o] * v[o];
    h1[(size_t)b * 512 + j] = fmaxf(acc, 0.f);
  }
}

__global__ __launch_bounds__(256)
void k_dec2(const float* __restrict__ w2, const float* __restrict__ b2,
            const float* __restrict__ h1, float* __restrict__ h2) {
  __shared__ float red[4][64][4];
  int t = threadIdx.x, lane = t & 63, strip = t >> 6;
  int j = blockIdx.x * 64 + lane, bs = blockIdx.y * 4;
  float acc[4] = {0.f, 0.f, 0.f, 0.f};
  const float* wr = w2 + (size_t)j * 512 + strip * 128;
  const float* hb = h1 + (size_t)bs * 512 + strip * 128;
  for (int k4 = 0; k4 < 32; ++k4) {
    float4 wv = *(const float4*)(wr + k4 * 4);
    const float* h0 = hb + k4 * 4;
#pragma unroll
    for (int q = 0; q < 4; ++q) {
      float4 hv = *(const float4*)(h0 + q * 512);
      acc[q] += wv.x * hv.x + wv.y * hv.y + wv.z * hv.z + wv.w * hv.w;
    }
  }
#pragma unroll
  for (int q = 0; q < 4; ++q) red[strip][lane][q] = acc[q];
  __syncthreads();
  if (strip == 0) {
    float bias = b2[j];
#pragma unroll
    for (int q = 0; q < 4; ++q) {
      float tot = red[0][lane][q] + red[1][lane][q] + red[2][lane][q] + red[3][lane][q] + bias;
      h2[(size_t)(bs + q) * 1024 + j] = fmaxf(tot, 0.f);
    }
  }
}

__global__ __launch_bounds__(256)
void k_dec3(const float* __restrict__ w3, const float* __restrict__ b3,
            const float* __restrict__ h2, float* __restrict__ dout) {
  __shared__ float red[4][64][4];
  int t = threadIdx.x, lane = t & 63, strip = t >> 6;
  int j = blockIdx.x * 64 + lane, bs = blockIdx.y * 4;
  float acc[4] = {0.f, 0.f, 0.f, 0.f};
  const float* wr = w3 + (size_t)j * 1024 + strip * 256;
  const float* hb = h2 + (size_t)bs * 1024 + strip * 256;
  for (int k4 = 0; k4 < 64; ++k4) {
    float4 wv = *(const float4*)(wr + k4 * 4);
    const float* h0 = hb + k4 * 4;
#pragma unroll
    for (int q = 0; q < 4; ++q) {
      float4 hv = *(const float4*)(h0 + q * 1024);
      acc[q] += wv.x * hv.x + wv.y * hv.y + wv.z * hv.z + wv.w * hv.w;
    }
  }
#pragma unroll
  for (int q = 0; q < 4; ++q) red[strip][lane][q] = acc[q];
  __syncthreads();
  if (strip == 0) {
    float bias = b3[j];
#pragma unroll
    for (int q = 0; q < 4; ++q) {
      float tot = red[0][lane][q] + red[1][lane][q] + red[2][lane][q] + red[3][lane][q] + bias;
      dout[(size_t)(bs + q) * 1184 + 160 + j] = 1.f / (1.f + expf(-tot));
    }
  }
}

// ---------------------------------------------------------------------------
extern "C" void kernel_launch(void* const* d_in, const int* in_sizes, int n_in,
                              void* d_out, int out_size, void* d_ws, size_t ws_size,
                              hipStream_t stream) {
  (void)in_sizes; (void)n_in; (void)out_size; (void)ws_size;
  const float* data = (const float*)d_in[0];
  const float* c1w  = (const float*)d_in[1];
  const float* c1b  = (const float*)d_in[2];
  const float* pw   = (const float*)d_in[3];
  const float* pb   = (const float*)d_in[4];
  const float* Wdc  = (const float*)d_in[5];
  const float* w1   = (const float*)d_in[6];
  const float* b1   = (const float*)d_in[7];
  const float* w2   = (const float*)d_in[8];
  const float* b2   = (const float*)d_in[9];
  const float* w3   = (const float*)d_in[10];
  const float* b3   = (const float*)d_in[11];
  float* out = (float*)d_out;
  float* ws  = (float*)d_ws;

  float* WT   = ws + OFF_WT;
  float* X1   = ws + OFF_X1;
  float* PU   = ws + OFF_PU;
  float* UHAT = ws + OFF_UHAT;
  float* U    = ws + OFF_U;
  float* BIJ  = ws + OFF_BIJ;
  float* CIJ  = ws + OFF_CIJ;
  float* SP   = ws + OFF_SP;
  float* VJ   = ws + OFF_VJ;
  int*   IDX  = (int*)(ws + OFF_IDX);
  float* H1   = ws + OFF_H1;
  float* H2   = ws + OFF_H2;

  k_transpose_w<<<dim3(256, 4), 256, 0, stream>>>(pw, WT);
  k_conv1<<<dim3(BATCH, 8), 256, 0, stream>>>(data, c1w, c1b, X1);
  k_prim<<<dim3(8, 8, 25), 256, 0, stream>>>(X1, WT, PU);
  k_ured<<<1600, 256, 0, stream>>>(PU, pb, U);
  k_squash<<<BATCH, 256, 0, stream>>>(U);                     // U -> u_sq in place
  k_uhat<<<256, 192, 0, stream>>>(Wdc, U, UHAT);              // clobbers WT/X1/PU (dead)

  for (int it = 0; it < 3; ++it) {
    if (it > 0) k_softc<<<10, 256, 0, stream>>>(BIJ, CIJ);
    k_sjpart<<<dim3(BATCH, 16), 192, 0, stream>>>(CIJ, UHAT, SP, it == 0 ? 1 : 0);
    k_sjred<<<BATCH, 192, 0, stream>>>(SP, VJ, out, it == 2 ? 1 : 0);
    if (it < 2) k_amean<<<256, 192, 0, stream>>>(UHAT, VJ, BIJ, it == 0 ? 1 : 0);
  }

  k_cls<<<1, 256, 0, stream>>>(VJ, IDX);
  k_dec1<<<BATCH, 256, 0, stream>>>(w1, b1, VJ, IDX, H1);
  k_dec2<<<dim3(16, 25), 256, 0, stream>>>(w2, b2, H1, H2);
  k_dec3<<<dim3(16, 25), 256, 0, stream>>>(w3, b3, H2, out);
}

// Round 11
// 1294.043 us; speedup vs baseline: 2.6946x; 2.6946x over previous
//
#include <hip/hip_runtime.h>
#include <cstdint>
#include <cstddef>

// ---------------------------------------------------------------------------
// CapsNet forward, f32 end-to-end (precision-critical: the sort-based squash
// flips discrete segments on ~1e-7 perturbations of s_j, so no bf16 on that
// path).
//
// Workspace phases (floats), peak footprint 33.2M fl:
//   A (prim):    WT[0..5.31M] X1[5.31..20.05M] PU[20.05..33.16M]
//   B (ured):    U[33.16..34.80M]
//   C (uhat):    UHAT[0..32.77M] + U
//   D (routing): UHAT + smalls[32.77M..33.23M]
// ---------------------------------------------------------------------------

#define BATCH 100

static const size_t OFF_WT   = 0;            // 256*81*256 = 5,308,416   (dead after prim)
static const size_t OFF_X1   = 5308416;      // 100*256*576 = 14,745,600 (dead after prim)
static const size_t OFF_PU   = 20054016;     // 8*100*2048*8 = 13,107,200 (dead after k_ured)
static const size_t OFF_UHAT = 0;            // 100*2048*160 = 32,768,000
static const size_t OFF_U    = 33161216;     // 100*2048*8 = 1,638,400 (dead after k_uhat)
static const size_t OFF_BIJ  = 32768000;     // 2048*10
static const size_t OFF_CIJ  = 32788480;     // 2048*10
static const size_t OFF_SP   = 32808960;     // 100*16*160 = 256,000
static const size_t OFF_VJ   = 33064960;     // 100*160
static const size_t OFF_IDX  = 33080960;     // 100 ints (128 slots)
static const size_t OFF_H1   = 33081088;     // 100*512
static const size_t OFF_H2   = 33132288;     // 100*1024 -> end 33,234,688

// piecewise-affine squash constants
#define PT1f -13.46416092f
#define PA1f 0.000242759f
#define PB1f 0.024488359f
#define PA2f 0.002769205f
#define PB2f 0.06089699f
#define PT3f 13.23405266f
#define PA3f -0.002828244f
#define PB3f 0.061313814f
#define PA4f -0.000219038f
#define PB4f 0.023874787f

#define DT1f -0.075410217f
#define DA1f -0.074520095f
#define DB1f 0.349297946f
#define DA2f -0.534473989f
#define DB2f 0.27196494f
#define DT3f 0.062207676f
#define DA3f 0.637642944f
#define DB3f 0.295330779f
#define DA4f 0.169344703f
#define DB4f 0.353784456f

// async global->LDS DMA (16 B per lane; LDS dest = wave-uniform base + lane*16)
#define GLDS16(gp, lp)                                                        \
  __builtin_amdgcn_global_load_lds(                                           \
      (const __attribute__((address_space(1))) void*)(gp),                    \
      (__attribute__((address_space(3))) void*)(lp), 16, 0, 0)

// ---------------------------------------------------------------------------
// w_t[(ci*81+tap)*256 + co]  <-  prim_w[co][ci][tap]
// ---------------------------------------------------------------------------
__global__ __launch_bounds__(256)
void k_transpose_w(const float* __restrict__ w, float* __restrict__ wt) {
  __shared__ float tile[64 * 82];
  int ci = blockIdx.x, co0 = blockIdx.y * 64, t = threadIdx.x;
  for (int f = t; f < 64 * 81; f += 256) {
    int col = f / 81, tap = f - col * 81;
    tile[col * 82 + tap] = w[(size_t)(co0 + col) * 20736 + (size_t)ci * 81 + tap];
  }
  __syncthreads();
  for (int g = t; g < 64 * 81; g += 256) {
    int tap = g / 64, col = g - tap * 64;
    wt[((size_t)ci * 81 + tap) * 256 + co0 + col] = tile[col * 82 + tap];
  }
}

// ---------------------------------------------------------------------------
// conv1 + bias + relu: data(100,1,32,32) -> x1(100,256,24,24)
// ---------------------------------------------------------------------------
__global__ __launch_bounds__(256)
void k_conv1(const float* __restrict__ data, const float* __restrict__ cw,
             const float* __restrict__ cb, float* __restrict__ x1) {
  __shared__ float img[1024];
  __shared__ float wl[81 * 32];     // [tap][c]
  int b = blockIdx.x, cg = blockIdx.y, t = threadIdx.x;
  for (int f = t; f < 1024; f += 256) img[f] = data[(size_t)b * 1024 + f];
  for (int f = t; f < 2592; f += 256) {
    int tap = f >> 5, c = f & 31;
    wl[f] = cw[(size_t)(cg * 32 + c) * 81 + tap];
  }
  __syncthreads();
  for (int task = t; task < 1152; task += 256) {
    int q = task % 144, cq = task / 144;
    int p0 = q * 4, oh = p0 / 24, ow0 = p0 % 24;
    float a[4][4];
#pragma unroll
    for (int i = 0; i < 4; ++i)
#pragma unroll
      for (int j = 0; j < 4; ++j) a[i][j] = 0.f;
    for (int kh = 0; kh < 9; ++kh) {
      const float* ir = &img[(oh + kh) * 32 + ow0];
      const float* wr = &wl[kh * 9 * 32 + cq * 4];
#pragma unroll
      for (int kw = 0; kw < 9; ++kw) {
        float4 wv = *(const float4*)(wr + kw * 32);
#pragma unroll
        for (int j = 0; j < 4; ++j) {
          float xv = ir[kw + j];
          a[0][j] = fmaf(wv.x, xv, a[0][j]);
          a[1][j] = fmaf(wv.y, xv, a[1][j]);
          a[2][j] = fmaf(wv.z, xv, a[2][j]);
          a[3][j] = fmaf(wv.w, xv, a[3][j]);
        }
      }
    }
#pragma unroll
    for (int cc = 0; cc < 4; ++cc) {
      int c = cg * 32 + cq * 4 + cc;
      float bias = cb[c];
      float4 o4 = make_float4(fmaxf(a[cc][0] + bias, 0.f), fmaxf(a[cc][1] + bias, 0.f),
                              fmaxf(a[cc][2] + bias, 0.f), fmaxf(a[cc][3] + bias, 0.f));
      *(float4*)&x1[((size_t)(b * 256 + c) * 24 + oh) * 24 + ow0] = o4;
    }
  }
}

// ---------------------------------------------------------------------------
// prim conv v11: x1(100,256,24,24) -> PU[split](100,2048,8), 9x9 stride 2.
// v7's 2-barrier structure + ASYNC global_load_lds staging (no VGPR
// round-trip -> nothing to spill; R8-R10's pipeline attempts all died on
// register allocation).
//   x in LDS: [tb][24 rows][28 fl] contiguous (row pad 24->28; reads are
//   2-way bank-aliased = free per m136). w: [tap][co32] contiguous.
//   Staging job j = t + 256*s -> lds byte 16*j: each wave's 64 lanes cover
//   one contiguous 1 KiB LDS window (the wave-uniform-base requirement).
// LDS: xsh 10752 B + wsh (oversized to 21632 B) = 32384 B -> 5 blocks/CU ->
// allocator VGPR budget 512/5 ~= 102 >= demand ~80 -> no 64-clamp, no spill.
// FMA order per output identical to v7 -> bitwise-same partials.
// ---------------------------------------------------------------------------
__global__ __launch_bounds__(256)
void k_prim(const float* __restrict__ x1, const float* __restrict__ wt,
            float* __restrict__ pu) {
  // wsh oversized: first 2592 floats used; tail pads LDS to pin occupancy
  // at 5 blocks/CU (VGPR budget 102 -- the R8/R10 spill fix).
  __shared__ float wsh[5408];           // used: 81*32 = 2592 fl (10368 B)
  __shared__ float xsh[2688];           // [tb][24 rows][28 fl]    (10752 B)
  int t = threadIdx.x;
  int tb = t >> 6, tl = t & 63;
  int coq = tl >> 3, oh = tl & 7;
  int ci_base = blockIdx.x * 32, cog = blockIdx.y, bq = blockIdx.z;
  int b = bq * 4 + tb;

  char* xshB = (char*)xsh;
  char* wshB = (char*)wsh;

  // ---- fixed per-thread DMA jobs ----
  // x: 672 chunks of 16 B (4 tb x 24 rows x 7 chunks); jobs t, t+256, t+512(<672)
  int xj0 = t, xj1 = t + 256, xj2 = t + 512;
  bool hx2 = (t < 160);
  const float* xg[3];
  {
    int js[3] = {xj0, xj1, hx2 ? xj2 : 0};
#pragma unroll
    for (int s = 0; s < 3; ++s) {
      int j = js[s];
      int tbj = j / 168, rem = j - tbj * 168;
      int row = rem / 7, ch = rem - row * 7;
      // chunk 6 (floats 24..27) overreads into the next row: harmless pad fill
      xg[s] = x1 + ((size_t)(bq * 4 + tbj) * 256 + ci_base) * 576 + row * 24 + ch * 4;
    }
  }
  // w: 648 chunks of 16 B (81 tap x 8 colq); jobs t, t+256, t+512(<648)
  bool hw2 = (t < 136);
  const float* wg[3];
  {
    int js[3] = {t, t + 256, hw2 ? t + 512 : 0};
#pragma unroll
    for (int s = 0; s < 3; ++s) {
      int j = js[s];
      int tap = j >> 3, cq = j & 7;
      wg[s] = wt + ((size_t)ci_base * 81 + tap) * 256 + cog * 32 + cq * 4;
    }
  }

  float acc[4][8];
#pragma unroll
  for (int i = 0; i < 4; ++i)
#pragma unroll
    for (int j = 0; j < 8; ++j) acc[i][j] = 0.f;

  const float* xrb = &xsh[tb * 672];
  const float* wb = &wsh[coq * 4];

#pragma unroll 1
  for (int ci = ci_base; ci < ci_base + 32; ++ci) {
    __syncthreads();                      // prev compute done reading LDS
    // async DMA this ci's tiles straight into LDS (no VGPR round-trip)
    GLDS16(xg[0], xshB + 16 * xj0);
    GLDS16(xg[1], xshB + 16 * xj1);
    if (hx2) GLDS16(xg[2], xshB + 16 * xj2);
    GLDS16(wg[0], wshB + 16 * t);
    GLDS16(wg[1], wshB + 16 * (t + 256));
    if (hw2) GLDS16(wg[2], wshB + 16 * (t + 512));
    xg[0] += 576; xg[1] += 576; xg[2] += 576;
    wg[0] += 81 * 256; wg[1] += 81 * 256; wg[2] += 81 * 256;
    __syncthreads();                      // vmcnt drain: copies landed
    // compute: kh fully unrolled, contiguous row reads (6 x b128 per kh)
#pragma unroll
    for (int kh = 0; kh < 9; ++kh) {
      const float* xe = xrb + (2 * oh + kh) * 28;
      float xr[24];
      *(float4*)&xr[0]  = *(const float4*)xe;
      *(float4*)&xr[4]  = *(const float4*)(xe + 4);
      *(float4*)&xr[8]  = *(const float4*)(xe + 8);
      *(float4*)&xr[12] = *(const float4*)(xe + 12);
      *(float4*)&xr[16] = *(const float4*)(xe + 16);
      *(float4*)&xr[20] = *(const float4*)(xe + 20);
      const float* wr = wb + kh * 288;
#pragma unroll
      for (int p = 0; p < 5; ++p) {                 // kw = 2p (even cols)
        float4 wv = *(const float4*)(wr + p * 64);
#pragma unroll
        for (int j = 0; j < 8; ++j) {
          float xv = xr[2 * (p + j)];
          acc[0][j] = fmaf(wv.x, xv, acc[0][j]);
          acc[1][j] = fmaf(wv.y, xv, acc[1][j]);
          acc[2][j] = fmaf(wv.z, xv, acc[2][j]);
          acc[3][j] = fmaf(wv.w, xv, acc[3][j]);
        }
      }
#pragma unroll
      for (int p = 0; p < 4; ++p) {                 // kw = 2p+1 (odd cols)
        float4 wv = *(const float4*)(wr + 32 + p * 64);
#pragma unroll
        for (int j = 0; j < 8; ++j) {
          float xv = xr[2 * (p + j) + 1];
          acc[0][j] = fmaf(wv.x, xv, acc[0][j]);
          acc[1][j] = fmaf(wv.y, xv, acc[1][j]);
          acc[2][j] = fmaf(wv.z, xv, acc[2][j]);
          acc[3][j] = fmaf(wv.w, xv, acc[3][j]);
        }
      }
    }
  }
  // partial write (no bias; k_ured adds it): pu[split][b][r=co*8+oh][ow]
  float* pp = pu + (((size_t)blockIdx.x * BATCH + b) * 2048 +
                    (cog * 32 + coq * 4) * 8 + oh) * 8;
#pragma unroll
  for (int cc = 0; cc < 4; ++cc) {
    *(float4*)(pp + cc * 64)     = make_float4(acc[cc][0], acc[cc][1], acc[cc][2], acc[cc][3]);
    *(float4*)(pp + cc * 64 + 4) = make_float4(acc[cc][4], acc[cc][5], acc[cc][6], acc[cc][7]);
  }
}

// u = sum of 8 partials (ci-ascending order) + bias
__global__ __launch_bounds__(256)
void k_ured(const float* __restrict__ pu, const float* __restrict__ pb,
            float* __restrict__ u) {
  int g4 = blockIdx.x * 256 + threadIdx.x;     // 409,600 float4s
  if (g4 >= 409600) return;
  size_t g = (size_t)g4 * 4;
  const size_t S = 1638400;
  float4 s = *(const float4*)(pu + g);
#pragma unroll
  for (int k = 1; k < 8; ++k) {
    float4 p = *(const float4*)(pu + (size_t)k * S + g);
    s.x += p.x; s.y += p.y; s.z += p.z; s.w += p.w;
  }
  int r = (int)((g >> 3) & 2047);
  float bias = pb[r >> 3];
  float4 o = make_float4(s.x + bias, s.y + bias, s.z + bias, s.w + bias);
  *(float4*)(u + g) = o;
}

// ---------------------------------------------------------------------------
// primary squash: stable bitonic sort per batch row + exact where-chain,
// then u_sq = mag * u in place.
// ---------------------------------------------------------------------------
__global__ __launch_bounds__(256)
void k_squash(float* __restrict__ u) {
  __shared__ float kv[2048];
  __shared__ int kid[2048];
  __shared__ int red[256];
  int b = blockIdx.x, t = threadIdx.x;
  for (int r = t; r < 2048; r += 256) {
    kv[r] = u[((size_t)b * 2048 + r) * 8];
    kid[r] = r;
  }
  __syncthreads();
  for (int size = 2; size <= 2048; size <<= 1) {
    for (int stride = size >> 1; stride > 0; stride >>= 1) {
#pragma unroll 1
      for (int s = 0; s < 4; ++s) {
        int i = t + s * 256;
        int pos = 2 * i - (i & (stride - 1));
        int q = pos + stride;
        float va = kv[pos], vb = kv[q];
        int ia = kid[pos], ib = kid[q];
        bool gt = (va > vb) || (va == vb && ia > ib);
        bool up = ((pos & size) == 0);
        if (gt == up) { kv[pos] = vb; kv[q] = va; kid[pos] = ib; kid[q] = ia; }
      }
      __syncthreads();
    }
  }
  int loc = 0;
#pragma unroll
  for (int s = 0; s < 8; ++s) loc += (kv[t + s * 256] < PT1f) ? 1 : 0;
  red[t] = loc; __syncthreads();
  for (int off = 128; off; off >>= 1) { if (t < off) red[t] += red[t + off]; __syncthreads(); }
  int i1 = red[0]; __syncthreads();
  float m1v[8];
  loc = 0;
#pragma unroll
  for (int s = 0; s < 8; ++s) {
    int p = t + s * 256;
    float v = kv[p];
    float m = (p < i1 - 1) ? (PA1f * v + PB1f) : v;
    m1v[s] = m;
    loc += (m < 0.f) ? 1 : 0;
  }
  red[t] = loc; __syncthreads();
  for (int off = 128; off; off >>= 1) { if (t < off) red[t] += red[t + off]; __syncthreads(); }
  int i2 = red[0]; __syncthreads();
  float m2v[8];
  loc = 0;
#pragma unroll
  for (int s = 0; s < 8; ++s) {
    int p = t + s * 256;
    float m = (p >= i1 && p < i2 - 1) ? (PA2f * m1v[s] + PB2f) : m1v[s];
    m2v[s] = m;
    loc += (m < PT3f) ? 1 : 0;
  }
  red[t] = loc; __syncthreads();
  for (int off = 128; off; off >>= 1) { if (t < off) red[t] += red[t + off]; __syncthreads(); }
  int i3 = red[0]; __syncthreads();
#pragma unroll
  for (int s = 0; s < 8; ++s) {
    int p = t + s * 256;
    float m = m2v[s];
    m = (p >= i2 && p < i3 - 1) ? (PA3f * m + PB3f) : m;
    m = (p >= i3 && p < 2047) ? (PA4f * m + PB4f) : m;
    int rid = kid[p];
    float* row = u + ((size_t)b * 2048 + rid) * 8;
    float4 lo = *(float4*)row;
    float4 hi = *(float4*)(row + 4);
    lo.x *= m; lo.y *= m; lo.z *= m; lo.w *= m;
    hi.x *= m; hi.y *= m; hi.z *= m; hi.w *= m;
    *(float4*)row = lo;
    *(float4*)(row + 4) = hi;
  }
}

// ---------------------------------------------------------------------------
// u_hat[b][r][c*16+o] = sum_i W_dc[r][c][o][i] * u_sq[b][r][i]
// ---------------------------------------------------------------------------
__global__ __launch_bounds__(192)
void k_uhat(const float* __restrict__ Wdc, const float* __restrict__ usq,
            float* __restrict__ uhat) {
  int t = threadIdx.x;
  if (t >= 160) return;
  int r0 = blockIdx.x * 8;
#pragma unroll 1
  for (int half = 0; half < 2; ++half) {
    int rb = r0 + half * 4;
    float4 wa[4], wb4[4];
#pragma unroll
    for (int rl = 0; rl < 4; ++rl) {
      const float* wp = Wdc + ((size_t)(rb + rl) * 160 + t) * 8;
      wa[rl]  = *(const float4*)wp;
      wb4[rl] = *(const float4*)(wp + 4);
    }
#pragma unroll 2
    for (int b = 0; b < BATCH; ++b) {
      const float* ub = usq + ((size_t)b * 2048 + rb) * 8;
      float* op = uhat + ((size_t)b * 2048 + rb) * 160 + t;
#pragma unroll
      for (int rl = 0; rl < 4; ++rl) {
        const float* us = ub + rl * 8;
        float v = us[0] * wa[rl].x + us[1] * wa[rl].y + us[2] * wa[rl].z + us[3] * wa[rl].w +
                  us[4] * wb4[rl].x + us[5] * wb4[rl].y + us[6] * wb4[rl].z + us[7] * wb4[rl].w;
        op[(size_t)rl * 160] = v;
      }
    }
  }
}

__global__ __launch_bounds__(256)
void k_softc(const float* __restrict__ bij, float* __restrict__ cij) {
  __shared__ float red[256];
  int c = blockIdx.x, t = threadIdx.x;
  float m = -3.402823466e38f;
  for (int r = t; r < 2048; r += 256) m = fmaxf(m, bij[r * 10 + c]);
  red[t] = m; __syncthreads();
  for (int off = 128; off; off >>= 1) { if (t < off) red[t] = fmaxf(red[t], red[t + off]); __syncthreads(); }
  m = red[0]; __syncthreads();
  float s = 0.f;
  for (int r = t; r < 2048; r += 256) s += expf(bij[r * 10 + c] - m);
  red[t] = s; __syncthreads();
  for (int off = 128; off; off >>= 1) { if (t < off) red[t] += red[t + off]; __syncthreads(); }
  s = red[0];
  for (int r = t; r < 2048; r += 256) cij[r * 10 + c] = expf(bij[r * 10 + c] - m) / s;
}

// it0: c_ij = softmax(zeros) = 1/2048 exactly -> uniform constant, no CIJ read
__global__ __launch_bounds__(192)
void k_sjpart(const float* __restrict__ cij, const float* __restrict__ uhat,
              float* __restrict__ sp, int it0) {
  __shared__ float cl[1280];
  int b = blockIdx.x, ch = blockIdx.y, t = threadIdx.x;
  if (!it0) {
    for (int f = t; f < 1280; f += 192) cl[f] = cij[(size_t)ch * 1280 + f];
  }
  __syncthreads();
  if (t < 160) {
    int c = t >> 4;
    float acc = 0.f;
    const float* up = uhat + ((size_t)b * 2048 + ch * 128) * 160 + t;
    if (it0) {
      const float cuni = 0.00048828125f;    // 1/2048 exact
#pragma unroll 4
      for (int rl = 0; rl < 128; ++rl) acc += cuni * up[(size_t)rl * 160];
    } else {
#pragma unroll 4
      for (int rl = 0; rl < 128; ++rl) acc += cl[rl * 10 + c] * up[(size_t)rl * 160];
    }
    sp[((size_t)b * 16 + ch) * 160 + t] = acc;
  }
}

__global__ __launch_bounds__(192)
void k_sjred(const float* __restrict__ sp, float* __restrict__ vj,
             float* __restrict__ dout, int finalit) {
  __shared__ float sl[160];
  __shared__ float fl[10];
  int b = blockIdx.x, t = threadIdx.x;
  if (t < 160) {
    float a = 0.f;
#pragma unroll
    for (int ch = 0; ch < 16; ++ch) a += sp[((size_t)b * 16 + ch) * 160 + t];
    sl[t] = a;
  }
  __syncthreads();
  if (t == 0) {
    float sv[10]; int rk[10];
    for (int c = 0; c < 10; ++c) sv[c] = sl[c * 16];
    for (int c = 0; c < 10; ++c) {
      int r = 0;
      for (int k = 0; k < 10; ++k)
        r += ((sv[k] < sv[c]) || (sv[k] == sv[c] && k < c)) ? 1 : 0;
      rk[c] = r;
    }
    int i1 = 0;
    for (int c = 0; c < 10; ++c) i1 += (sv[c] < DT1f) ? 1 : 0;
    float m1[10];
    for (int c = 0; c < 10; ++c) m1[c] = (rk[c] < i1 - 1) ? (DA1f * sv[c] + DB1f) : sv[c];
    int i2 = 0;
    for (int c = 0; c < 10; ++c) i2 += (m1[c] < 0.f) ? 1 : 0;
    float m2[10];
    for (int c = 0; c < 10; ++c)
      m2[c] = (rk[c] >= i1 && rk[c] < i2 - 1) ? (DA2f * m1[c] + DB2f) : m1[c];
    int i3 = 0;
    for (int c = 0; c < 10; ++c) i3 += (m2[c] < DT3f) ? 1 : 0;
    for (int c = 0; c < 10; ++c) {
      float m = (rk[c] >= i2 && rk[c] < i3 - 1) ? (DA3f * m2[c] + DB3f) : m2[c];
      m = (rk[c] >= i3 && rk[c] < 9) ? (DA4f * m + DB4f) : m;
      fl[c] = m;
    }
  }
  __syncthreads();
  if (t < 160) {
    int c = t >> 4, o = t & 15;
    float fv = fl[c];
    float v = fv * ((o == 0) ? fv : sl[t]);
    vj[(size_t)b * 160 + t] = v;
    if (finalit) dout[(size_t)b * 1184 + t] = v;
  }
}

// b-outer / r-inner -> per-b reads are 5120 B contiguous. Accumulation order
// per (r,t) unchanged (b-sequential, then o-shuffle).
__global__ __launch_bounds__(192)
void k_amean(const float* __restrict__ uhat, const float* __restrict__ vj,
             float* __restrict__ bij, int first) {
  __shared__ float vl[16000];
  int t = threadIdx.x, r0 = blockIdx.x * 8;
  for (int f = t; f < 16000; f += 192) vl[f] = vj[f];
  __syncthreads();
  if (t < 160) {
    int c = t >> 4;
    float acc[8];
#pragma unroll
    for (int rl = 0; rl < 8; ++rl) acc[rl] = 0.f;
    const float* up0 = uhat + (size_t)r0 * 160 + t;
#pragma unroll 2
    for (int b = 0; b < BATCH; ++b) {
      float vv = vl[b * 160 + t];
      const float* up = up0 + (size_t)b * 327680;
#pragma unroll
      for (int rl = 0; rl < 8; ++rl)
        acc[rl] = fmaf(up[(size_t)rl * 160], vv, acc[rl]);
    }
#pragma unroll
    for (int rl = 0; rl < 8; ++rl) {
      float a = acc[rl];
      for (int off = 8; off; off >>= 1) a += __shfl_down(a, off, 16);
      if ((t & 15) == 0) {
        int r = r0 + rl;
        float val = a / 100.0f;
        bij[r * 10 + c] = first ? val : (bij[r * 10 + c] + val);
      }
    }
  }
}

__global__ __launch_bounds__(256)
void k_cls(const float* __restrict__ vj, int* __restrict__ idxg) {
  __shared__ float cl[1000];
  __shared__ float cm[10];
  __shared__ float cs[10];
  int t = threadIdx.x;
  for (int f = t; f < 1000; f += 256) {
    int b = f / 10, c = f - b * 10;
    float s = 0.f;
#pragma unroll
    for (int o = 0; o < 16; ++o) {
      float v = vj[(size_t)b * 160 + c * 16 + o];
      s += v * v;
    }
    cl[f] = sqrtf(s);
  }
  __syncthreads();
  if (t < 10) {
    float m = -3.402823466e38f;
    for (int b = 0; b < BATCH; ++b) m = fmaxf(m, cl[b * 10 + t]);
    float s = 0.f;
    for (int b = 0; b < BATCH; ++b) s += expf(cl[b * 10 + t] - m);
    cm[t] = m; cs[t] = s;
  }
  __syncthreads();
  for (int b = t; b < BATCH; b += 256) {
    float best = -1.f; int bi = 0;
    for (int c = 0; c < 10; ++c) {
      float val = expf(cl[b * 10 + c] - cm[c]) / cs[c];
      if (val > best) { best = val; bi = c; }
    }
    idxg[b] = bi;
  }
}

__global__ __launch_bounds__(256)
void k_dec1(const float* __restrict__ w1, const float* __restrict__ b1,
            const float* __restrict__ vj, const int* __restrict__ idxg,
            float* __restrict__ h1) {
  int b = blockIdx.x, t = threadIdx.x;
  int id = idxg[b];
  const float* v = vj + (size_t)b * 160 + id * 16;
  for (int j = t; j < 512; j += 256) {
    float acc = b1[j];
    const float* wr = w1 + (size_t)j * 160 + id * 16;
#pragma unroll
    for (int o = 0; o < 16; ++o) acc += wr[o] * v[o];
    h1[(size_t)b * 512 + j] = fmaxf(acc, 0.f);
  }
}

__global__ __launch_bounds__(256)
void k_dec2(const float* __restrict__ w2, const float* __restrict__ b2,
            const float* __restrict__ h1, float* __restrict__ h2) {
  __shared__ float red[4][64][4];
  int t = threadIdx.x, lane = t & 63, strip = t >> 6;
  int j = blockIdx.x * 64 + lane, bs = blockIdx.y * 4;
  float acc[4] = {0.f, 0.f, 0.f, 0.f};
  const float* wr = w2 + (size_t)j * 512 + strip * 128;
  const float* hb = h1 + (size_t)bs * 512 + strip * 128;
  for (int k4 = 0; k4 < 32; ++k4) {
    float4 wv = *(const float4*)(wr + k4 * 4);
    const float* h0 = hb + k4 * 4;
#pragma unroll
    for (int q = 0; q < 4; ++q) {
      float4 hv = *(const float4*)(h0 + q * 512);
      acc[q] += wv.x * hv.x + wv.y * hv.y + wv.z * hv.z + wv.w * hv.w;
    }
  }
#pragma unroll
  for (int q = 0; q < 4; ++q) red[strip][lane][q] = acc[q];
  __syncthreads();
  if (strip == 0) {
    float bias = b2[j];
#pragma unroll
    for (int q = 0; q < 4; ++q) {
      float tot = red[0][lane][q] + red[1][lane][q] + red[2][lane][q] + red[3][lane][q] + bias;
      h2[(size_t)(bs + q) * 1024 + j] = fmaxf(tot, 0.f);
    }
  }
}

__global__ __launch_bounds__(256)
void k_dec3(const float* __restrict__ w3, const float* __restrict__ b3,
            const float* __restrict__ h2, float* __restrict__ dout) {
  __shared__ float red[4][64][4];
  int t = threadIdx.x, lane = t & 63, strip = t >> 6;
  int j = blockIdx.x * 64 + lane, bs = blockIdx.y * 4;
  float acc[4] = {0.f, 0.f, 0.f, 0.f};
  const float* wr = w3 + (size_t)j * 1024 + strip * 256;
  const float* hb = h2 + (size_t)bs * 1024 + strip * 256;
  for (int k4 = 0; k4 < 64; ++k4) {
    float4 wv = *(const float4*)(wr + k4 * 4);
    const float* h0 = hb + k4 * 4;
#pragma unroll
    for (int q = 0; q < 4; ++q) {
      float4 hv = *(const float4*)(h0 + q * 1024);
      acc[q] += wv.x * hv.x + wv.y * hv.y + wv.z * hv.z + wv.w * hv.w;
    }
  }
#pragma unroll
  for (int q = 0; q < 4; ++q) red[strip][lane][q] = acc[q];
  __syncthreads();
  if (strip == 0) {
    float bias = b3[j];
#pragma unroll
    for (int q = 0; q < 4; ++q) {
      float tot = red[0][lane][q] + red[1][lane][q] + red[2][lane][q] + red[3][lane][q] + bias;
      dout[(size_t)(bs + q) * 1184 + 160 + j] = 1.f / (1.f + expf(-tot));
    }
  }
}

// ---------------------------------------------------------------------------
extern "C" void kernel_launch(void* const* d_in, const int* in_sizes, int n_in,
                              void* d_out, int out_size, void* d_ws, size_t ws_size,
                              hipStream_t stream) {
  (void)in_sizes; (void)n_in; (void)out_size; (void)ws_size;
  const float* data = (const float*)d_in[0];
  const float* c1w  = (const float*)d_in[1];
  const float* c1b  = (const float*)d_in[2];
  const float* pw   = (const float*)d_in[3];
  const float* pb   = (const float*)d_in[4];
  const float* Wdc  = (const float*)d_in[5];
  const float* w1   = (const float*)d_in[6];
  const float* b1   = (const float*)d_in[7];
  const float* w2   = (const float*)d_in[8];
  const float* b2   = (const float*)d_in[9];
  const float* w3   = (const float*)d_in[10];
  const float* b3   = (const float*)d_in[11];
  float* out = (float*)d_out;
  float* ws  = (float*)d_ws;

  float* WT   = ws + OFF_WT;
  float* X1   = ws + OFF_X1;
  float* PU   = ws + OFF_PU;
  float* UHAT = ws + OFF_UHAT;
  float* U    = ws + OFF_U;
  float* BIJ  = ws + OFF_BIJ;
  float* CIJ  = ws + OFF_CIJ;
  float* SP   = ws + OFF_SP;
  float* VJ   = ws + OFF_VJ;
  int*   IDX  = (int*)(ws + OFF_IDX);
  float* H1   = ws + OFF_H1;
  float* H2   = ws + OFF_H2;

  k_transpose_w<<<dim3(256, 4), 256, 0, stream>>>(pw, WT);
  k_conv1<<<dim3(BATCH, 8), 256, 0, stream>>>(data, c1w, c1b, X1);
  k_prim<<<dim3(8, 8, 25), 256, 0, stream>>>(X1, WT, PU);
  k_ured<<<1600, 256, 0, stream>>>(PU, pb, U);
  k_squash<<<BATCH, 256, 0, stream>>>(U);                     // U -> u_sq in place
  k_uhat<<<256, 192, 0, stream>>>(Wdc, U, UHAT);              // clobbers WT/X1/PU (dead)

  for (int it = 0; it < 3; ++it) {
    if (it > 0) k_softc<<<10, 256, 0, stream>>>(BIJ, CIJ);
    k_sjpart<<<dim3(BATCH, 16), 192, 0, stream>>>(CIJ, UHAT, SP, it == 0 ? 1 : 0);
    k_sjred<<<BATCH, 192, 0, stream>>>(SP, VJ, out, it == 2 ? 1 : 0);
    if (it < 2) k_amean<<<256, 192, 0, stream>>>(UHAT, VJ, BIJ, it == 0 ? 1 : 0);
  }

  k_cls<<<1, 256, 0, stream>>>(VJ, IDX);
  k_dec1<<<BATCH, 256, 0, stream>>>(w1, b1, VJ, IDX, H1);
  k_dec2<<<dim3(16, 25), 256, 0, stream>>>(w2, b2, H1, H2);
  k_dec3<<<dim3(16, 25), 256, 0, stream>>>(w3, b3, H2, out);
}